// Round 1
// baseline (44.547 us; speedup 1.0000x reference)
//
#include <hip/hip_runtime.h>

// Raw image moments m_pq = sum_{y,x} I[y,x] * x^p * y^q for the 10 moments
// up to order 3, matching the JAX reference's output order:
//   m00 m10 m01 m20 m11 m02 m30 m21 m12 m03
// Input: [4096, 128, 128, 1] float32. Output: [4096, 10] float32.
//
// One block (256 threads) per image. Each thread loads 16 float4 (coalesced,
// 16 B/lane), accumulates 10 register partial sums, then wave shuffle-reduce
// + cross-wave LDS reduce. Memory-bound: 256 MiB read, ~43 us roofline.

#define IMG_ELEMS 16384   // 128*128
#define F4_PER_IMG 4096   // 16384/4

__global__ __launch_bounds__(256) void RawMoments_kernel(
    const float* __restrict__ in, float* __restrict__ out)
{
    const int b = blockIdx.x;
    const float4* img = reinterpret_cast<const float4*>(in + (size_t)b * IMG_ELEMS);
    const int tid = threadIdx.x;

    float acc[10];
#pragma unroll
    for (int i = 0; i < 10; ++i) acc[i] = 0.0f;

#pragma unroll
    for (int i = 0; i < 16; ++i) {
        const int f = tid + i * 256;           // float4 index in [0, 4096)
        const float4 v = img[f];
        const float y  = (float)(f >> 5);      // row = f / 32 (32 float4 per row)
        const float xb = (float)((f & 31) << 2);
        const float y2 = y * y;
        const float y3 = y2 * y;
        const float vals[4] = {v.x, v.y, v.z, v.w};
#pragma unroll
        for (int j = 0; j < 4; ++j) {
            const float p  = vals[j];
            const float x  = xb + (float)j;
            const float x2 = x * x;
            const float x3 = x2 * x;
            const float px = p * x;
            const float py = p * y;
            acc[0] += p;            // m00
            acc[1] += px;           // m10
            acc[2] += py;           // m01
            acc[3] += p * x2;       // m20
            acc[4] += px * y;       // m11
            acc[5] += p * y2;       // m02
            acc[6] += p * x3;       // m30
            acc[7] += p * x2 * y;   // m21
            acc[8] += px * y2;      // m12
            acc[9] += p * y3;       // m03
        }
    }

    // Intra-wave (64-lane) butterfly-free shfl_down tree reduce.
#pragma unroll
    for (int off = 32; off > 0; off >>= 1) {
#pragma unroll
        for (int i = 0; i < 10; ++i)
            acc[i] += __shfl_down(acc[i], off, 64);
    }

    // Cross-wave reduce through LDS (4 waves x 10 floats).
    __shared__ float red[4][10];
    const int wave = tid >> 6;
    const int lane = tid & 63;
    if (lane == 0) {
#pragma unroll
        for (int i = 0; i < 10; ++i) red[wave][i] = acc[i];
    }
    __syncthreads();
    if (tid < 10) {
        const float s = red[0][tid] + red[1][tid] + red[2][tid] + red[3][tid];
        out[(size_t)b * 10 + tid] = s;
    }
}

extern "C" void kernel_launch(void* const* d_in, const int* in_sizes, int n_in,
                              void* d_out, int out_size, void* d_ws, size_t ws_size,
                              hipStream_t stream)
{
    const float* in = (const float*)d_in[0];
    float* out = (float*)d_out;
    const int n_imgs = in_sizes[0] / IMG_ELEMS;   // 4096
    RawMoments_kernel<<<n_imgs, 256, 0, stream>>>(in, out);
}